// Round 16
// baseline (410.495 us; speedup 1.0000x reference)
//
#include <hip/hip_runtime.h>
#include <hip/hip_fp16.h>
#include <math.h>

#define N_NODES   100000
#define N_EDGES   400000
#define N_INC     1600000
#define N_GRAPHS  512
#define ATOM_DIM  92
#define NODE_DIM  64
#define H_DIM     128
#define NUM_LAYERS 3
#define BN_EPS    1e-5f

#define NBUCK     391      // = ceil(400000/1024) = ceil(100000/256)
#define PCHUNK    2048     // items per partition block (256 thr x 8)
#define NCHP      ((N_INC + PCHUNK - 1) / PCHUNK)   // 782 chunks
#define MM_BLOCKS 1568     // blocks for MFMA kernels

struct alignas(8)  half4 { __half2 a, b; };
struct alignas(16) half8 { __half2 a, b, c, d; };
typedef __attribute__((ext_vector_type(8))) float float8;
typedef __attribute__((ext_vector_type(2))) float float2v;
typedef __attribute__((ext_vector_type(4))) float f32x4;
typedef _Float16 f16x8 __attribute__((ext_vector_type(8)));

__device__ __forceinline__ float softplus_f(float x) {
    return fmaxf(x, 0.f) + log1pf(expf(-fabsf(x)));
}

__device__ __forceinline__ float8 cvt8(half8 v) {
    float2 p0 = __half22float2(v.a), p1 = __half22float2(v.b);
    float2 p2 = __half22float2(v.c), p3 = __half22float2(v.d);
    float8 r;
    r[0] = p0.x; r[1] = p0.y; r[2] = p1.x; r[3] = p1.y;
    r[4] = p2.x; r[5] = p2.y; r[6] = p3.x; r[7] = p3.y;
    return r;
}
__device__ __forceinline__ half8 cvt16(float8 v) {
    half8 r;
    r.a = __floats2half2_rn(v[0], v[1]);
    r.b = __floats2half2_rn(v[2], v[3]);
    r.c = __floats2half2_rn(v[4], v[5]);
    r.d = __floats2half2_rn(v[6], v[7]);
    return r;
}

// fp8 e4m3 (OCP) pack/unpack via gfx950 HW converters
__device__ __forceinline__ float8 fp8x8_to_f32u(unsigned lo, unsigned hi) {
    float2v l0 = __builtin_amdgcn_cvt_pk_f32_fp8((int)lo, false);
    float2v h0 = __builtin_amdgcn_cvt_pk_f32_fp8((int)lo, true);
    float2v l1 = __builtin_amdgcn_cvt_pk_f32_fp8((int)hi, false);
    float2v h1 = __builtin_amdgcn_cvt_pk_f32_fp8((int)hi, true);
    float8 r;
    r[0] = l0.x; r[1] = l0.y; r[2] = h0.x; r[3] = h0.y;
    r[4] = l1.x; r[5] = l1.y; r[6] = h1.x; r[7] = h1.y;
    return r;
}
__device__ __forceinline__ float8 fp8x8_to_f32(uint2 v) {
    return fp8x8_to_f32u(v.x, v.y);
}
__device__ __forceinline__ uint2 f32_to_fp8x8(float8 v) {
    int a = 0, b = 0;
    a = __builtin_amdgcn_cvt_pk_fp8_f32(v[0], v[1], a, false);
    a = __builtin_amdgcn_cvt_pk_fp8_f32(v[2], v[3], a, true);
    b = __builtin_amdgcn_cvt_pk_fp8_f32(v[4], v[5], b, false);
    b = __builtin_amdgcn_cvt_pk_fp8_f32(v[6], v[7], b, true);
    uint2 r; r.x = (unsigned)a; r.y = (unsigned)b;
    return r;
}

// ---------------- embedding GEMM via MFMA: h = x @ W_emb + b (fp32 in, fp8 out) ----------------

__global__ void __launch_bounds__(256) embed_mfma(
        const float* __restrict__ x, const float* __restrict__ W,
        const float* __restrict__ bvec, uint2* __restrict__ h8) {
    __shared__ half8 so8[4][16][9];   // per-wave 16x72 halves transpose staging
    int tid = threadIdx.x;
    int w = tid >> 6, lane = tid & 63;
    int l15 = lane & 15, rg = lane >> 4;
    __half* so_h = (__half*)so8[w];

    f16x8 bf[4][3];
    #pragma unroll
    for (int c = 0; c < 4; ++c)
        #pragma unroll
        for (int kk = 0; kk < 3; ++kk)
            #pragma unroll
            for (int j = 0; j < 8; ++j) {
                int k = kk * 32 + rg * 8 + j;
                bf[c][kk][j] = (k < ATOM_DIM) ? (_Float16)W[k * 64 + c * 16 + l15]
                                              : (_Float16)0.f;
            }
    float bias[4];
    #pragma unroll
    for (int c = 0; c < 4; ++c) bias[c] = bvec[c * 16 + l15];

    int wave_global = blockIdx.x * 4 + w;
    for (int tile = wave_global; tile < N_NODES / 16; tile += MM_BLOCKS * 4) {
        int n0 = tile * 16;
        const float* xrow = x + (size_t)(n0 + l15) * ATOM_DIM;
        f16x8 af[3];
        #pragma unroll
        for (int kk = 0; kk < 3; ++kk) {
            int k0 = kk * 32 + rg * 8;
            if (k0 + 8 <= ATOM_DIM) {
                float4 v0 = *(const float4*)&xrow[k0];
                float4 v1 = *(const float4*)&xrow[k0 + 4];
                af[kk][0] = (_Float16)v0.x; af[kk][1] = (_Float16)v0.y;
                af[kk][2] = (_Float16)v0.z; af[kk][3] = (_Float16)v0.w;
                af[kk][4] = (_Float16)v1.x; af[kk][5] = (_Float16)v1.y;
                af[kk][6] = (_Float16)v1.z; af[kk][7] = (_Float16)v1.w;
            } else {
                float4 v0 = *(const float4*)&xrow[88];
                af[kk][0] = (_Float16)v0.x; af[kk][1] = (_Float16)v0.y;
                af[kk][2] = (_Float16)v0.z; af[kk][3] = (_Float16)v0.w;
                af[kk][4] = (_Float16)0.f;  af[kk][5] = (_Float16)0.f;
                af[kk][6] = (_Float16)0.f;  af[kk][7] = (_Float16)0.f;
            }
        }
        #pragma unroll
        for (int c = 0; c < 4; ++c) {
            f32x4 acc = {0.f, 0.f, 0.f, 0.f};
            acc = __builtin_amdgcn_mfma_f32_16x16x32_f16(af[0], bf[c][0], acc, 0, 0, 0);
            acc = __builtin_amdgcn_mfma_f32_16x16x32_f16(af[1], bf[c][1], acc, 0, 0, 0);
            acc = __builtin_amdgcn_mfma_f32_16x16x32_f16(af[2], bf[c][2], acc, 0, 0, 0);
            #pragma unroll
            for (int i = 0; i < 4; ++i)
                so_h[(rg * 4 + i) * 72 + c * 16 + l15] = __float2half_rn(acc[i] + bias[c]);
        }
        #pragma unroll
        for (int it = 0; it < 2; ++it) {
            int row = (lane >> 3) + it * 8;
            half8 v = *(half8*)&so_h[row * 72 + (lane & 7) * 8];
            h8[(size_t)(n0 + row) * 8 + (lane & 7)] = f32_to_fp8x8(cvt8(v));
        }
    }
}

// ---------------- CSR build: dual deterministic counting sort (u32 staging) ----------------
// E staging word: (local_edge_key[10b] << 17) | node_id[17b]
// N staging word: (local_node_key[8b] << 19) | edge_id[19b]

__global__ void __launch_bounds__(256) part_hist_dual(
        const int* __restrict__ ekey, const int* __restrict__ nkey,
        int* __restrict__ histsE, int* __restrict__ histsN) {
    __shared__ int hE[NBUCK];
    __shared__ int hN[NBUCK];
    int tid = threadIdx.x;
    int base = blockIdx.x * PCHUNK;
    for (int i = tid; i < NBUCK; i += 256) { hE[i] = 0; hN[i] = 0; }
    __syncthreads();
    #pragma unroll
    for (int k = 0; k < 8; ++k) {
        int i = base + tid + k * 256;
        if (i < N_INC) {
            atomicAdd(&hE[ekey[i] >> 10], 1);
            atomicAdd(&hN[nkey[i] >> 8], 1);
        }
    }
    __syncthreads();
    for (int i = tid; i < NBUCK; i += 256) {
        histsE[(size_t)blockIdx.x * NBUCK + i] = hE[i];
        histsN[(size_t)blockIdx.x * NBUCK + i] = hN[i];
    }
}

__global__ void __launch_bounds__(256) col_scan_dual(
        int* __restrict__ histsE, int* __restrict__ histsN,
        int* __restrict__ colsumE, int* __restrict__ colsumN) {
    __shared__ int ws[256];
    int which = blockIdx.x >= NBUCK;
    int i = which ? (blockIdx.x - NBUCK) : blockIdx.x;
    int* hists = which ? histsN : histsE;
    int* colsum = which ? colsumN : colsumE;
    int tid = threadIdx.x;
    int v[4];
    int loc = 0;
    #pragma unroll
    for (int k = 0; k < 4; ++k) {
        int b = tid * 4 + k;
        v[k] = (b < NCHP) ? hists[(size_t)b * NBUCK + i] : 0;
        loc += v[k];
    }
    ws[tid] = loc;
    __syncthreads();
    for (int off = 1; off < 256; off <<= 1) {
        int t = (tid >= off) ? ws[tid - off] : 0;
        __syncthreads();
        ws[tid] += t;
        __syncthreads();
    }
    int run = ws[tid] - loc;
    if (tid == 255) colsum[i] = ws[255];
    #pragma unroll
    for (int k = 0; k < 4; ++k) {
        int b = tid * 4 + k;
        if (b < NCHP) hists[(size_t)b * NBUCK + i] = run;
        run += v[k];
    }
}

__global__ void bbase_scan_dual(const int* __restrict__ colsumE, const int* __restrict__ colsumN,
                                int* __restrict__ bbaseE, int* __restrict__ bbaseN) {
    __shared__ int sh[512];
    const int* colsum = blockIdx.x ? colsumN : colsumE;
    int* bbase = blockIdx.x ? bbaseN : bbaseE;
    int tid = threadIdx.x;   // 512 threads
    int v = (tid < NBUCK) ? colsum[tid] : 0;
    sh[tid] = v;
    __syncthreads();
    for (int off = 1; off < 512; off <<= 1) {
        int t = (tid >= off) ? sh[tid - off] : 0;
        __syncthreads();
        sh[tid] += t;
        __syncthreads();
    }
    if (tid <= NBUCK)
        bbase[tid] = (tid == 0) ? 0 : sh[tid - 1];
}

__global__ void __launch_bounds__(256) part_scatter_dual(
        const int* __restrict__ ekey, const int* __restrict__ nkey,
        const int* __restrict__ histsE, const int* __restrict__ histsN,
        const int* __restrict__ bbaseE, const int* __restrict__ bbaseN,
        unsigned* __restrict__ stagingE, unsigned* __restrict__ stagingN) {
    __shared__ int curE[NBUCK];
    __shared__ int curN[NBUCK];
    int tid = threadIdx.x;
    int base = blockIdx.x * PCHUNK;
    int kE[8], kN[8];
    #pragma unroll
    for (int k = 0; k < 8; ++k) {
        int i = base + tid + k * 256;
        bool ok = (i < N_INC);
        kE[k] = ok ? ekey[i] : -1;
        kN[k] = ok ? nkey[i] : 0;
    }
    for (int i = tid; i < NBUCK; i += 256) {
        curE[i] = bbaseE[i] + histsE[(size_t)blockIdx.x * NBUCK + i];
        curN[i] = bbaseN[i] + histsN[(size_t)blockIdx.x * NBUCK + i];
    }
    __syncthreads();
    #pragma unroll
    for (int k = 0; k < 8; ++k) {
        if (kE[k] >= 0) {
            int pe = atomicAdd(&curE[kE[k] >> 10], 1);
            stagingE[pe] = ((unsigned)(kE[k] & 1023) << 17) | (unsigned)kN[k];
            int pn = atomicAdd(&curN[kN[k] >> 8], 1);
            stagingN[pn] = ((unsigned)(kN[k] & 255) << 19) | (unsigned)kE[k];
        }
    }
}

// one block per bucket: per-id histogram -> offsets + 1/deg + in-bucket payload scatter
template<int RANGE, int PAYBITS>
__device__ void finalize_impl(const unsigned* __restrict__ staging,
                              const int* __restrict__ bbase, int b,
                              int nIds, float* __restrict__ inv,
                              int* __restrict__ off, int* __restrict__ list,
                              int* hist, int* wsum) {
    const int PER = RANGE / 256;
    const unsigned PAYMASK = (1u << PAYBITS) - 1u;
    int tid = threadIdx.x;
    int s = bbase[b], t = bbase[b + 1];
    int id0 = b * RANGE;
    for (int i = tid; i < RANGE; i += 256) hist[i] = 0;
    __syncthreads();
    for (int j = s + tid; j < t; j += 256) {
        unsigned key = staging[j] >> PAYBITS;
        atomicAdd(&hist[key], 1);
    }
    __syncthreads();
    int base0 = tid * PER;
    int vals[PER];
    int local = 0;
    #pragma unroll
    for (int k = 0; k < PER; ++k) { vals[k] = hist[base0 + k]; local += vals[k]; }
    wsum[tid] = local;
    __syncthreads();
    for (int o = 1; o < 256; o <<= 1) {
        int tv = (tid >= o) ? wsum[tid - o] : 0;
        __syncthreads();
        wsum[tid] += tv;
        __syncthreads();
    }
    int run = wsum[tid] - local;
    #pragma unroll
    for (int k = 0; k < PER; ++k) {
        int id = id0 + base0 + k;
        int gpos = s + run;
        if (id < nIds) {
            off[id] = gpos;
            inv[id] = vals[k] > 0 ? 1.f / (float)vals[k] : 0.f;
        } else if (id == nIds) {
            off[nIds] = gpos;
        }
        hist[base0 + k] = gpos;
        run += vals[k];
    }
    __syncthreads();
    for (int j = s + tid; j < t; j += 256) {
        unsigned it = staging[j];
        unsigned key = it >> PAYBITS;
        int pos = atomicAdd(&hist[key], 1);
        list[pos] = (int)(it & PAYMASK);
    }
}

__global__ void __launch_bounds__(256) bucket_finalize_dual(
        const unsigned* __restrict__ stagingE, const unsigned* __restrict__ stagingN,
        const int* __restrict__ bbaseE, const int* __restrict__ bbaseN,
        float* __restrict__ binv, float* __restrict__ dinv,
        int* __restrict__ eoff, int* __restrict__ noff,
        int* __restrict__ elist, int* __restrict__ nlist) {
    __shared__ int hist[1024];
    __shared__ int wsum[256];
    if (blockIdx.x < NBUCK) {
        finalize_impl<1024, 17>(stagingE, bbaseE, blockIdx.x, N_EDGES, binv, eoff, elist,
                                hist, wsum);
    } else {
        finalize_impl<256, 19>(stagingN, bbaseN, blockIdx.x - NBUCK, N_NODES, dinv, noff, nlist,
                               hist, wsum);
    }
}

// ---------------- gather aggregations (4-lane groups, 16B/lane requests) ----------------

// 4-lane group per edge (64 edges/block); lane q owns 16B (16 fp8 features)
__global__ void __launch_bounds__(256) edge_agg(
        const int* __restrict__ eoff, const int* __restrict__ elist,
        const uint4* __restrict__ h16B, const float* __restrict__ binv,
        uint4* __restrict__ efeat16B) {
    int e = blockIdx.x * 64 + (threadIdx.x >> 2);
    if (e >= N_EDGES) return;
    int q = threadIdx.x & 3;
    int s = eoff[e], t = eoff[e + 1];
    float8 alo = (float8)0.f, ahi = (float8)0.f;
    float8 blo = (float8)0.f, bhi = (float8)0.f;
    int j = s;
    for (; j + 1 < t; j += 2) {
        int n0 = __ldg(&elist[j]), n1 = __ldg(&elist[j + 1]);
        uint4 v0 = __ldg(&h16B[(size_t)n0 * 4 + q]);
        uint4 v1 = __ldg(&h16B[(size_t)n1 * 4 + q]);
        alo += fp8x8_to_f32u(v0.x, v0.y); ahi += fp8x8_to_f32u(v0.z, v0.w);
        blo += fp8x8_to_f32u(v1.x, v1.y); bhi += fp8x8_to_f32u(v1.z, v1.w);
    }
    if (j < t) {
        uint4 v0 = __ldg(&h16B[(size_t)__ldg(&elist[j]) * 4 + q]);
        alo += fp8x8_to_f32u(v0.x, v0.y); ahi += fp8x8_to_f32u(v0.z, v0.w);
    }
    alo += blo; ahi += bhi;
    float bv = binv[e];
    alo *= bv; ahi *= bv;
    uint2 lo = f32_to_fp8x8(alo), hi = f32_to_fp8x8(ahi);
    uint4 st; st.x = lo.x; st.y = lo.y; st.z = hi.x; st.w = hi.y;
    efeat16B[(size_t)e * 4 + q] = st;
}

// 4-lane group per node (64 nodes/block); 4-deep accumulators; writes fp16 agg row
__global__ void __launch_bounds__(256) node_agg(
        const int* __restrict__ noff, const int* __restrict__ nlist,
        const uint4* __restrict__ efeat16B, const float* __restrict__ dinv,
        __half* __restrict__ agg16) {
    int n = blockIdx.x * 64 + (threadIdx.x >> 2);
    if (n >= N_NODES) return;
    int q = threadIdx.x & 3;
    int s = noff[n], t = noff[n + 1];
    float8 l0 = (float8)0.f, h0 = (float8)0.f;
    float8 l1 = (float8)0.f, h1 = (float8)0.f;
    float8 l2 = (float8)0.f, h2 = (float8)0.f;
    float8 l3 = (float8)0.f, h3 = (float8)0.f;
    int j = s;
    for (; j + 3 < t; j += 4) {
        int e0 = __ldg(&nlist[j]),     e1 = __ldg(&nlist[j + 1]);
        int e2 = __ldg(&nlist[j + 2]), e3 = __ldg(&nlist[j + 3]);
        uint4 v0 = __ldg(&efeat16B[(size_t)e0 * 4 + q]);
        uint4 v1 = __ldg(&efeat16B[(size_t)e1 * 4 + q]);
        uint4 v2 = __ldg(&efeat16B[(size_t)e2 * 4 + q]);
        uint4 v3 = __ldg(&efeat16B[(size_t)e3 * 4 + q]);
        l0 += fp8x8_to_f32u(v0.x, v0.y); h0 += fp8x8_to_f32u(v0.z, v0.w);
        l1 += fp8x8_to_f32u(v1.x, v1.y); h1 += fp8x8_to_f32u(v1.z, v1.w);
        l2 += fp8x8_to_f32u(v2.x, v2.y); h2 += fp8x8_to_f32u(v2.z, v2.w);
        l3 += fp8x8_to_f32u(v3.x, v3.y); h3 += fp8x8_to_f32u(v3.z, v3.w);
    }
    for (; j < t; ++j) {
        uint4 v0 = __ldg(&efeat16B[(size_t)__ldg(&nlist[j]) * 4 + q]);
        l0 += fp8x8_to_f32u(v0.x, v0.y); h0 += fp8x8_to_f32u(v0.z, v0.w);
    }
    l0 += l1; l2 += l3; l0 += l2;
    h0 += h1; h2 += h3; h0 += h2;
    float dv = dinv[n];
    l0 *= dv; h0 *= dv;
    *(half8*)&agg16[(size_t)n * 64 + q * 16]     = cvt16(l0);
    *(half8*)&agg16[(size_t)n * 64 + q * 16 + 8] = cvt16(h0);
}

// ---------------- dense GEMM via MFMA: outr = agg @ W + b (masked); stats -> partials ----------------

__global__ void __launch_bounds__(256) gemm_bn_kernel(
        const __half* __restrict__ agg16, const float* __restrict__ dinv,
        const float* __restrict__ W, const float* __restrict__ bvec,
        __half* __restrict__ outr16, float* __restrict__ partials) {
    __shared__ half8 so8[4][16][9];
    __shared__ float sred[4][128];
    int tid = threadIdx.x;
    int w = tid >> 6, lane = tid & 63;
    int l15 = lane & 15, rg = lane >> 4;
    __half* so_h = (__half*)so8[w];

    f16x8 bf[4][2];
    #pragma unroll
    for (int c = 0; c < 4; ++c)
        #pragma unroll
        for (int kk = 0; kk < 2; ++kk)
            #pragma unroll
            for (int j = 0; j < 8; ++j) {
                int k = kk * 32 + rg * 8 + j;
                bf[c][kk][j] = (_Float16)W[k * 64 + c * 16 + l15];
            }
    float bias[4];
    #pragma unroll
    for (int c = 0; c < 4; ++c) bias[c] = bvec[c * 16 + l15];

    float sa[4] = {0.f, 0.f, 0.f, 0.f}, sb[4] = {0.f, 0.f, 0.f, 0.f};
    int wave_global = blockIdx.x * 4 + w;
    for (int tile = wave_global; tile < N_NODES / 16; tile += MM_BLOCKS * 4) {
        int n0 = tile * 16;
        f16x8 a0 = *(const f16x8*)&agg16[(size_t)(n0 + l15) * 64 + rg * 8];
        f16x8 a1 = *(const f16x8*)&agg16[(size_t)(n0 + l15) * 64 + 32 + rg * 8];
        float dv[4];
        #pragma unroll
        for (int i = 0; i < 4; ++i) dv[i] = dinv[n0 + rg * 4 + i];
        #pragma unroll
        for (int c = 0; c < 4; ++c) {
            f32x4 acc = {0.f, 0.f, 0.f, 0.f};
            acc = __builtin_amdgcn_mfma_f32_16x16x32_f16(a0, bf[c][0], acc, 0, 0, 0);
            acc = __builtin_amdgcn_mfma_f32_16x16x32_f16(a1, bf[c][1], acc, 0, 0, 0);
            #pragma unroll
            for (int i = 0; i < 4; ++i) {
                float vv = (dv[i] > 0.f) ? (acc[i] + bias[c]) : 0.f;
                sa[c] += vv; sb[c] += vv * vv;
                so_h[(rg * 4 + i) * 72 + c * 16 + l15] = __float2half_rn(vv);
            }
        }
        #pragma unroll
        for (int it = 0; it < 2; ++it) {
            int row = (lane >> 3) + it * 8;
            half8 v = *(half8*)&so_h[row * 72 + (lane & 7) * 8];
            *(half8*)&outr16[(size_t)(n0 + row) * 64 + (lane & 7) * 8] = v;
        }
    }
    #pragma unroll
    for (int c = 0; c < 4; ++c) {
        sa[c] += __shfl_xor(sa[c], 16); sa[c] += __shfl_xor(sa[c], 32);
        sb[c] += __shfl_xor(sb[c], 16); sb[c] += __shfl_xor(sb[c], 32);
    }
    if (rg == 0) {
        #pragma unroll
        for (int c = 0; c < 4; ++c) {
            sred[w][c * 16 + l15]      = sa[c];
            sred[w][64 + c * 16 + l15] = sb[c];
        }
    }
    __syncthreads();
    if (tid < 128) {
        float v = sred[0][tid] + sred[1][tid] + sred[2][tid] + sred[3][tid];
        partials[(size_t)blockIdx.x * 128 + tid] = v;
    }
}

// ---------------- reduce partials + BN finalize: 64 blocks, one feature each ----------------

__global__ void __launch_bounds__(256) reduce_bnfin(
        const float* __restrict__ partials, const float* __restrict__ gamma,
        const float* __restrict__ beta, float* __restrict__ scsh) {
    __shared__ float ra[256];
    __shared__ float rb[256];
    int f = blockIdx.x, tid = threadIdx.x;
    float a = 0.f, b = 0.f;
    for (int j = tid; j < MM_BLOCKS; j += 256) {
        a += partials[(size_t)j * 128 + f];
        b += partials[(size_t)j * 128 + 64 + f];
    }
    ra[tid] = a; rb[tid] = b;
    __syncthreads();
    for (int s = 128; s > 0; s >>= 1) {
        if (tid < s) { ra[tid] += ra[tid + s]; rb[tid] += rb[tid + s]; }
        __syncthreads();
    }
    if (tid == 0) {
        const float invN = 1.f / (float)N_NODES;
        float mean = ra[0] * invN;
        float var  = rb[0] * invN - mean * mean;
        var = fmaxf(var, 0.f);
        float sc = gamma[f] * rsqrtf(var + BN_EPS);
        scsh[f]      = sc;
        scsh[64 + f] = beta[f] - mean * sc;
    }
}

// ---------------- BN apply + softplus (fp16 in, fp8 out) ----------------

__global__ void apply_kernel(const half8* __restrict__ outr8, const float* __restrict__ scsh,
                             uint2* __restrict__ h8) {
    int gid = blockIdx.x * 256 + threadIdx.x;   // over N_NODES*8 octets
    if (gid >= N_NODES * 8) return;
    int qq = gid & 7;
    float8 v = cvt8(outr8[gid]);
    float4 sc0 = ((const float4*)scsh)[qq * 2];
    float4 sc1 = ((const float4*)scsh)[qq * 2 + 1];
    float4 sh0 = ((const float4*)(scsh + 64))[qq * 2];
    float4 sh1 = ((const float4*)(scsh + 64))[qq * 2 + 1];
    float8 r;
    r[0] = softplus_f(fmaf(v[0], sc0.x, sh0.x));
    r[1] = softplus_f(fmaf(v[1], sc0.y, sh0.y));
    r[2] = softplus_f(fmaf(v[2], sc0.z, sh0.z));
    r[3] = softplus_f(fmaf(v[3], sc0.w, sh0.w));
    r[4] = softplus_f(fmaf(v[4], sc1.x, sh1.x));
    r[5] = softplus_f(fmaf(v[5], sc1.y, sh1.y));
    r[6] = softplus_f(fmaf(v[6], sc1.z, sh1.z));
    r[7] = softplus_f(fmaf(v[7], sc1.w, sh1.w));
    h8[gid] = f32_to_fp8x8(r);
}

// ---------------- fused pooling + head (batch is sorted; bounds inline) ----------------

__global__ void pool_head_kernel(const uint2* __restrict__ h8, const int* __restrict__ batch,
                                 const float* __restrict__ fcW, const float* __restrict__ fcb,
                                 const float* __restrict__ fcoW, const float* __restrict__ fcob,
                                 float* __restrict__ out) {
    __shared__ float8 part[32][8];
    __shared__ float p[64];
    __shared__ float red[128];
    __shared__ int seg[2];
    int g = blockIdx.x, tid = threadIdx.x;
    if (tid < 2) {
        int target = g + tid;
        int lo = 0, hi = N_NODES;
        while (lo < hi) {
            int mid = (lo + hi) >> 1;
            if (batch[mid] < target) lo = mid + 1; else hi = mid;
        }
        seg[tid] = lo;
    }
    __syncthreads();
    int s = seg[0], t = seg[1];
    int r = tid >> 3, q = tid & 7;   // 32 row slots x 8 octets
    float8 acc = (float8)0.f;
    for (int n = s + r; n < t; n += 32)
        acc += fp8x8_to_f32(__ldg(&h8[(size_t)n * 8 + q]));
    part[r][q] = acc;
    __syncthreads();
    for (int st = 16; st >= 1; st >>= 1) {
        if (r < st) part[r][q] += part[r + st][q];
        __syncthreads();
    }
    if (tid < 8) {
        float c = fmaxf((float)(t - s), 1.f);
        float8 v = part[0][tid];
        #pragma unroll
        for (int jj = 0; jj < 8; ++jj)
            p[tid * 8 + jj] = softplus_f(v[jj] / c);
    }
    __syncthreads();
    if (tid < 128) {
        float a = fcb[tid];
        #pragma unroll
        for (int k = 0; k < 64; ++k)
            a = fmaf(p[k], fcW[k * H_DIM + tid], a);
        red[tid] = softplus_f(a) * fcoW[tid];
    }
    __syncthreads();
    for (int st = 64; st > 0; st >>= 1) {
        if (tid < st) red[tid] += red[tid + st];
        __syncthreads();
    }
    if (tid == 0) out[g] = red[0] + fcob[0];
}

// ---------------- launch ----------------

extern "C" void kernel_launch(void* const* d_in, const int* in_sizes, int n_in,
                              void* d_out, int out_size, void* d_ws, size_t ws_size,
                              hipStream_t stream) {
    const float* x      = (const float*)d_in[0];
    const float* W_emb  = (const float*)d_in[1];
    const float* b_emb  = (const float*)d_in[2];
    const float* conv_W = (const float*)d_in[3];
    const float* conv_b = (const float*)d_in[4];
    const float* bn_g   = (const float*)d_in[5];
    const float* bn_b   = (const float*)d_in[6];
    const float* fc_W   = (const float*)d_in[7];
    const float* fc_b   = (const float*)d_in[8];
    const float* fco_W  = (const float*)d_in[9];
    const float* fco_b  = (const float*)d_in[10];
    const int* node_idx = (const int*)d_in[11];
    const int* edge_idx = (const int*)d_in[12];
    const int* batch    = (const int*)d_in[13];
    float* out = (float*)d_out;

    // ---- workspace layout ----
    uint2*  h8      = (uint2*)d_ws;                             // 800K uint2 (6.4 MB fp8)
    __half* outr16  = (__half*)(h8 + (size_t)N_NODES * 8);      // 6.4M halves
    __half* agg16   = outr16 + (size_t)N_NODES * 64;            // 6.4M halves
    uint2*  efeat8  = (uint2*)(agg16 + (size_t)N_NODES * 64);   // 3.2M uint2 (25.6 MB fp8)
    unsigned* stagingE = (unsigned*)(efeat8 + (size_t)N_EDGES * 8); // 1.6M u32
    unsigned* stagingN = stagingE + N_INC;                      // 1.6M u32
    float* binv    = (float*)(stagingN + N_INC);                // 400K
    float* dinv    = binv   + N_EDGES;                          // 100K
    float* scsh    = dinv   + N_NODES;                          // 128
    float* partials= scsh   + 128;                              // MM_BLOCKS*128
    int*   eoff    = (int*)(partials + (size_t)MM_BLOCKS * 128); // 400K+1
    int*   noff    = eoff  + N_EDGES + 1;                       // 100K+1
    int*   histsE  = noff  + N_NODES + 1;                       // NCHP*NBUCK
    int*   histsN  = histsE + (size_t)NCHP * NBUCK;             // NCHP*NBUCK
    int*   colsumE = histsN + (size_t)NCHP * NBUCK;             // NBUCK
    int*   colsumN = colsumE + NBUCK;                           // NBUCK
    int*   bbaseE  = colsumN + NBUCK;                           // NBUCK+1
    int*   bbaseN  = bbaseE + NBUCK + 1;                        // NBUCK+1
    int*   elist   = bbaseN + NBUCK + 1;                        // 1.6M
    int*   nlist   = elist + N_INC;                             // 1.6M

    // ---- CSR build: dual deterministic counting sort (no global atomics, u32 staging) ----
    part_hist_dual<<<NCHP, 256, 0, stream>>>(edge_idx, node_idx, histsE, histsN);
    col_scan_dual<<<2 * NBUCK, 256, 0, stream>>>(histsE, histsN, colsumE, colsumN);
    bbase_scan_dual<<<2, 512, 0, stream>>>(colsumE, colsumN, bbaseE, bbaseN);
    part_scatter_dual<<<NCHP, 256, 0, stream>>>(edge_idx, node_idx, histsE, histsN,
                                                bbaseE, bbaseN, stagingE, stagingN);
    bucket_finalize_dual<<<2 * NBUCK, 256, 0, stream>>>(stagingE, stagingN, bbaseE, bbaseN,
                                                        binv, dinv, eoff, noff, elist, nlist);

    // ---- embedding (MFMA, fp8 out) ----
    embed_mfma<<<MM_BLOCKS, 256, 0, stream>>>(x, W_emb, b_emb, h8);

    // ---- 3 hypergraph conv layers: agg = P h; out = agg@W + b; BN; softplus ----
    for (int l = 0; l < NUM_LAYERS; ++l) {
        const float* Wl = conv_W + (size_t)l * NODE_DIM * NODE_DIM;
        const float* bl = conv_b + (size_t)l * NODE_DIM;

        edge_agg<<<(N_EDGES + 63) / 64, 256, 0, stream>>>(eoff, elist, (const uint4*)h8,
                                                          binv, (uint4*)efeat8);
        node_agg<<<(N_NODES + 63) / 64, 256, 0, stream>>>(noff, nlist, (const uint4*)efeat8,
                                                          dinv, agg16);
        gemm_bn_kernel<<<MM_BLOCKS, 256, 0, stream>>>(agg16, dinv, Wl, bl, outr16, partials);
        reduce_bnfin<<<64, 256, 0, stream>>>(partials, bn_g + (size_t)l * 64,
                                             bn_b + (size_t)l * 64, scsh);
        apply_kernel<<<(N_NODES * 8 + 255) / 256, 256, 0, stream>>>((const half8*)outr16, scsh, h8);
    }

    // ---- fused pooling + head ----
    pool_head_kernel<<<N_GRAPHS, 256, 0, stream>>>(h8, batch, fc_W, fc_b, fco_W, fco_b, out);
}

// Round 18
// 397.831 us; speedup vs baseline: 1.0318x; 1.0318x over previous
//
#include <hip/hip_runtime.h>
#include <hip/hip_fp16.h>
#include <math.h>

#define N_NODES   100000
#define N_EDGES   400000
#define N_INC     1600000
#define N_GRAPHS  512
#define ATOM_DIM  92
#define NODE_DIM  64
#define H_DIM     128
#define NUM_LAYERS 3
#define BN_EPS    1e-5f

#define NBUCK     391      // = ceil(400000/1024) = ceil(100000/256)
#define PCHUNK    2048     // items per partition block (256 thr x 8)
#define NCHP      ((N_INC + PCHUNK - 1) / PCHUNK)   // 782 chunks
#define MM_BLOCKS 1568     // blocks for embed MFMA kernel
#define NG_BLOCKS ((N_NODES + 63) / 64)   // 1563 blocks for fused node_gemm

struct alignas(8)  half4 { __half2 a, b; };
struct alignas(16) half8 { __half2 a, b, c, d; };
typedef __attribute__((ext_vector_type(8))) float float8;
typedef __attribute__((ext_vector_type(2))) float float2v;
typedef __attribute__((ext_vector_type(4))) float f32x4;
typedef _Float16 f16x8 __attribute__((ext_vector_type(8)));

__device__ __forceinline__ float softplus_f(float x) {
    return fmaxf(x, 0.f) + log1pf(expf(-fabsf(x)));
}

__device__ __forceinline__ float8 cvt8(half8 v) {
    float2 p0 = __half22float2(v.a), p1 = __half22float2(v.b);
    float2 p2 = __half22float2(v.c), p3 = __half22float2(v.d);
    float8 r;
    r[0] = p0.x; r[1] = p0.y; r[2] = p1.x; r[3] = p1.y;
    r[4] = p2.x; r[5] = p2.y; r[6] = p3.x; r[7] = p3.y;
    return r;
}
__device__ __forceinline__ half8 cvt16(float8 v) {
    half8 r;
    r.a = __floats2half2_rn(v[0], v[1]);
    r.b = __floats2half2_rn(v[2], v[3]);
    r.c = __floats2half2_rn(v[4], v[5]);
    r.d = __floats2half2_rn(v[6], v[7]);
    return r;
}

// fp8 e4m3 (OCP) pack/unpack via gfx950 HW converters
__device__ __forceinline__ float8 fp8x8_to_f32u(unsigned lo, unsigned hi) {
    float2v l0 = __builtin_amdgcn_cvt_pk_f32_fp8((int)lo, false);
    float2v h0 = __builtin_amdgcn_cvt_pk_f32_fp8((int)lo, true);
    float2v l1 = __builtin_amdgcn_cvt_pk_f32_fp8((int)hi, false);
    float2v h1 = __builtin_amdgcn_cvt_pk_f32_fp8((int)hi, true);
    float8 r;
    r[0] = l0.x; r[1] = l0.y; r[2] = h0.x; r[3] = h0.y;
    r[4] = l1.x; r[5] = l1.y; r[6] = h1.x; r[7] = h1.y;
    return r;
}
__device__ __forceinline__ float8 fp8x8_to_f32(uint2 v) {
    return fp8x8_to_f32u(v.x, v.y);
}
__device__ __forceinline__ uint2 f32_to_fp8x8(float8 v) {
    int a = 0, b = 0;
    a = __builtin_amdgcn_cvt_pk_fp8_f32(v[0], v[1], a, false);
    a = __builtin_amdgcn_cvt_pk_fp8_f32(v[2], v[3], a, true);
    b = __builtin_amdgcn_cvt_pk_fp8_f32(v[4], v[5], b, false);
    b = __builtin_amdgcn_cvt_pk_fp8_f32(v[6], v[7], b, true);
    uint2 r; r.x = (unsigned)a; r.y = (unsigned)b;
    return r;
}

// ---------------- embedding GEMM via MFMA: h = x @ W_emb + b (fp32 in, fp8 out) ----------------

__global__ void __launch_bounds__(256) embed_mfma(
        const float* __restrict__ x, const float* __restrict__ W,
        const float* __restrict__ bvec, uint2* __restrict__ h8) {
    __shared__ half8 so8[4][16][9];   // per-wave 16x72 halves transpose staging
    int tid = threadIdx.x;
    int w = tid >> 6, lane = tid & 63;
    int l15 = lane & 15, rg = lane >> 4;
    __half* so_h = (__half*)so8[w];

    f16x8 bf[4][3];
    #pragma unroll
    for (int c = 0; c < 4; ++c)
        #pragma unroll
        for (int kk = 0; kk < 3; ++kk)
            #pragma unroll
            for (int j = 0; j < 8; ++j) {
                int k = kk * 32 + rg * 8 + j;
                bf[c][kk][j] = (k < ATOM_DIM) ? (_Float16)W[k * 64 + c * 16 + l15]
                                              : (_Float16)0.f;
            }
    float bias[4];
    #pragma unroll
    for (int c = 0; c < 4; ++c) bias[c] = bvec[c * 16 + l15];

    int wave_global = blockIdx.x * 4 + w;
    for (int tile = wave_global; tile < N_NODES / 16; tile += MM_BLOCKS * 4) {
        int n0 = tile * 16;
        const float* xrow = x + (size_t)(n0 + l15) * ATOM_DIM;
        f16x8 af[3];
        #pragma unroll
        for (int kk = 0; kk < 3; ++kk) {
            int k0 = kk * 32 + rg * 8;
            if (k0 + 8 <= ATOM_DIM) {
                float4 v0 = *(const float4*)&xrow[k0];
                float4 v1 = *(const float4*)&xrow[k0 + 4];
                af[kk][0] = (_Float16)v0.x; af[kk][1] = (_Float16)v0.y;
                af[kk][2] = (_Float16)v0.z; af[kk][3] = (_Float16)v0.w;
                af[kk][4] = (_Float16)v1.x; af[kk][5] = (_Float16)v1.y;
                af[kk][6] = (_Float16)v1.z; af[kk][7] = (_Float16)v1.w;
            } else {
                float4 v0 = *(const float4*)&xrow[88];
                af[kk][0] = (_Float16)v0.x; af[kk][1] = (_Float16)v0.y;
                af[kk][2] = (_Float16)v0.z; af[kk][3] = (_Float16)v0.w;
                af[kk][4] = (_Float16)0.f;  af[kk][5] = (_Float16)0.f;
                af[kk][6] = (_Float16)0.f;  af[kk][7] = (_Float16)0.f;
            }
        }
        #pragma unroll
        for (int c = 0; c < 4; ++c) {
            f32x4 acc = {0.f, 0.f, 0.f, 0.f};
            acc = __builtin_amdgcn_mfma_f32_16x16x32_f16(af[0], bf[c][0], acc, 0, 0, 0);
            acc = __builtin_amdgcn_mfma_f32_16x16x32_f16(af[1], bf[c][1], acc, 0, 0, 0);
            acc = __builtin_amdgcn_mfma_f32_16x16x32_f16(af[2], bf[c][2], acc, 0, 0, 0);
            #pragma unroll
            for (int i = 0; i < 4; ++i)
                so_h[(rg * 4 + i) * 72 + c * 16 + l15] = __float2half_rn(acc[i] + bias[c]);
        }
        #pragma unroll
        for (int it = 0; it < 2; ++it) {
            int row = (lane >> 3) + it * 8;
            half8 v = *(half8*)&so_h[row * 72 + (lane & 7) * 8];
            h8[(size_t)(n0 + row) * 8 + (lane & 7)] = f32_to_fp8x8(cvt8(v));
        }
    }
}

// ---------------- CSR build: dual deterministic counting sort (u32 staging) ----------------
// E staging word: (local_edge_key[10b] << 17) | node_id[17b]
// N staging word: (local_node_key[8b] << 19) | edge_id[19b]

__global__ void __launch_bounds__(256) part_hist_dual(
        const int* __restrict__ ekey, const int* __restrict__ nkey,
        int* __restrict__ histsE, int* __restrict__ histsN) {
    __shared__ int hE[NBUCK];
    __shared__ int hN[NBUCK];
    int tid = threadIdx.x;
    int base = blockIdx.x * PCHUNK;
    for (int i = tid; i < NBUCK; i += 256) { hE[i] = 0; hN[i] = 0; }
    __syncthreads();
    #pragma unroll
    for (int k = 0; k < 8; ++k) {
        int i = base + tid + k * 256;
        if (i < N_INC) {
            atomicAdd(&hE[ekey[i] >> 10], 1);
            atomicAdd(&hN[nkey[i] >> 8], 1);
        }
    }
    __syncthreads();
    for (int i = tid; i < NBUCK; i += 256) {
        histsE[(size_t)blockIdx.x * NBUCK + i] = hE[i];
        histsN[(size_t)blockIdx.x * NBUCK + i] = hN[i];
    }
}

__global__ void __launch_bounds__(256) col_scan_dual(
        int* __restrict__ histsE, int* __restrict__ histsN,
        int* __restrict__ colsumE, int* __restrict__ colsumN) {
    __shared__ int ws[256];
    int which = blockIdx.x >= NBUCK;
    int i = which ? (blockIdx.x - NBUCK) : blockIdx.x;
    int* hists = which ? histsN : histsE;
    int* colsum = which ? colsumN : colsumE;
    int tid = threadIdx.x;
    int v[4];
    int loc = 0;
    #pragma unroll
    for (int k = 0; k < 4; ++k) {
        int b = tid * 4 + k;
        v[k] = (b < NCHP) ? hists[(size_t)b * NBUCK + i] : 0;
        loc += v[k];
    }
    ws[tid] = loc;
    __syncthreads();
    for (int off = 1; off < 256; off <<= 1) {
        int t = (tid >= off) ? ws[tid - off] : 0;
        __syncthreads();
        ws[tid] += t;
        __syncthreads();
    }
    int run = ws[tid] - loc;
    if (tid == 255) colsum[i] = ws[255];
    #pragma unroll
    for (int k = 0; k < 4; ++k) {
        int b = tid * 4 + k;
        if (b < NCHP) hists[(size_t)b * NBUCK + i] = run;
        run += v[k];
    }
}

__global__ void bbase_scan_dual(const int* __restrict__ colsumE, const int* __restrict__ colsumN,
                                int* __restrict__ bbaseE, int* __restrict__ bbaseN) {
    __shared__ int sh[512];
    const int* colsum = blockIdx.x ? colsumN : colsumE;
    int* bbase = blockIdx.x ? bbaseN : bbaseE;
    int tid = threadIdx.x;   // 512 threads
    int v = (tid < NBUCK) ? colsum[tid] : 0;
    sh[tid] = v;
    __syncthreads();
    for (int off = 1; off < 512; off <<= 1) {
        int t = (tid >= off) ? sh[tid - off] : 0;
        __syncthreads();
        sh[tid] += t;
        __syncthreads();
    }
    if (tid <= NBUCK)
        bbase[tid] = (tid == 0) ? 0 : sh[tid - 1];
}

__global__ void __launch_bounds__(256) part_scatter_dual(
        const int* __restrict__ ekey, const int* __restrict__ nkey,
        const int* __restrict__ histsE, const int* __restrict__ histsN,
        const int* __restrict__ bbaseE, const int* __restrict__ bbaseN,
        unsigned* __restrict__ stagingE, unsigned* __restrict__ stagingN) {
    __shared__ int curE[NBUCK];
    __shared__ int curN[NBUCK];
    int tid = threadIdx.x;
    int base = blockIdx.x * PCHUNK;
    int kE[8], kN[8];
    #pragma unroll
    for (int k = 0; k < 8; ++k) {
        int i = base + tid + k * 256;
        bool ok = (i < N_INC);
        kE[k] = ok ? ekey[i] : -1;
        kN[k] = ok ? nkey[i] : 0;
    }
    for (int i = tid; i < NBUCK; i += 256) {
        curE[i] = bbaseE[i] + histsE[(size_t)blockIdx.x * NBUCK + i];
        curN[i] = bbaseN[i] + histsN[(size_t)blockIdx.x * NBUCK + i];
    }
    __syncthreads();
    #pragma unroll
    for (int k = 0; k < 8; ++k) {
        if (kE[k] >= 0) {
            int pe = atomicAdd(&curE[kE[k] >> 10], 1);
            stagingE[pe] = ((unsigned)(kE[k] & 1023) << 17) | (unsigned)kN[k];
            int pn = atomicAdd(&curN[kN[k] >> 8], 1);
            stagingN[pn] = ((unsigned)(kN[k] & 255) << 19) | (unsigned)kE[k];
        }
    }
}

template<int RANGE, int PAYBITS>
__device__ void finalize_impl(const unsigned* __restrict__ staging,
                              const int* __restrict__ bbase, int b,
                              int nIds, float* __restrict__ inv,
                              int* __restrict__ off, int* __restrict__ list,
                              int* hist, int* wsum) {
    const int PER = RANGE / 256;
    const unsigned PAYMASK = (1u << PAYBITS) - 1u;
    int tid = threadIdx.x;
    int s = bbase[b], t = bbase[b + 1];
    int id0 = b * RANGE;
    for (int i = tid; i < RANGE; i += 256) hist[i] = 0;
    __syncthreads();
    for (int j = s + tid; j < t; j += 256) {
        unsigned key = staging[j] >> PAYBITS;
        atomicAdd(&hist[key], 1);
    }
    __syncthreads();
    int base0 = tid * PER;
    int vals[PER];
    int local = 0;
    #pragma unroll
    for (int k = 0; k < PER; ++k) { vals[k] = hist[base0 + k]; local += vals[k]; }
    wsum[tid] = local;
    __syncthreads();
    for (int o = 1; o < 256; o <<= 1) {
        int tv = (tid >= o) ? wsum[tid - o] : 0;
        __syncthreads();
        wsum[tid] += tv;
        __syncthreads();
    }
    int run = wsum[tid] - local;
    #pragma unroll
    for (int k = 0; k < PER; ++k) {
        int id = id0 + base0 + k;
        int gpos = s + run;
        if (id < nIds) {
            off[id] = gpos;
            inv[id] = vals[k] > 0 ? 1.f / (float)vals[k] : 0.f;
        } else if (id == nIds) {
            off[nIds] = gpos;
        }
        hist[base0 + k] = gpos;
        run += vals[k];
    }
    __syncthreads();
    for (int j = s + tid; j < t; j += 256) {
        unsigned it = staging[j];
        unsigned key = it >> PAYBITS;
        int pos = atomicAdd(&hist[key], 1);
        list[pos] = (int)(it & PAYMASK);
    }
}

__global__ void __launch_bounds__(256) bucket_finalize_dual(
        const unsigned* __restrict__ stagingE, const unsigned* __restrict__ stagingN,
        const int* __restrict__ bbaseE, const int* __restrict__ bbaseN,
        float* __restrict__ binv, float* __restrict__ dinv,
        int* __restrict__ eoff, int* __restrict__ noff,
        int* __restrict__ elist, int* __restrict__ nlist) {
    __shared__ int hist[1024];
    __shared__ int wsum[256];
    if (blockIdx.x < NBUCK) {
        finalize_impl<1024, 17>(stagingE, bbaseE, blockIdx.x, N_EDGES, binv, eoff, elist,
                                hist, wsum);
    } else {
        finalize_impl<256, 19>(stagingN, bbaseN, blockIdx.x - NBUCK, N_NODES, dinv, noff, nlist,
                               hist, wsum);
    }
}

// ---------------- edge aggregation (4-lane groups, 16B/lane requests) ----------------

__global__ void __launch_bounds__(256) edge_agg(
        const int* __restrict__ eoff, const int* __restrict__ elist,
        const uint4* __restrict__ h16B, const float* __restrict__ binv,
        uint4* __restrict__ efeat16B) {
    int e = blockIdx.x * 64 + (threadIdx.x >> 2);
    if (e >= N_EDGES) return;
    int q = threadIdx.x & 3;
    int s = eoff[e], t = eoff[e + 1];
    float8 alo = (float8)0.f, ahi = (float8)0.f;
    float8 blo = (float8)0.f, bhi = (float8)0.f;
    int j = s;
    for (; j + 1 < t; j += 2) {
        int n0 = __ldg(&elist[j]), n1 = __ldg(&elist[j + 1]);
        uint4 v0 = __ldg(&h16B[(size_t)n0 * 4 + q]);
        uint4 v1 = __ldg(&h16B[(size_t)n1 * 4 + q]);
        alo += fp8x8_to_f32u(v0.x, v0.y); ahi += fp8x8_to_f32u(v0.z, v0.w);
        blo += fp8x8_to_f32u(v1.x, v1.y); bhi += fp8x8_to_f32u(v1.z, v1.w);
    }
    if (j < t) {
        uint4 v0 = __ldg(&h16B[(size_t)__ldg(&elist[j]) * 4 + q]);
        alo += fp8x8_to_f32u(v0.x, v0.y); ahi += fp8x8_to_f32u(v0.z, v0.w);
    }
    alo += blo; ahi += bhi;
    float bv = binv[e];
    alo *= bv; ahi *= bv;
    uint2 lo = f32_to_fp8x8(alo), hi = f32_to_fp8x8(ahi);
    uint4 st; st.x = lo.x; st.y = lo.y; st.z = hi.x; st.w = hi.y;
    efeat16B[(size_t)e * 4 + q] = st;
}

// ---------------- fused node aggregation + MFMA GEMM + BN partials ----------------
// Block = 256 thr = 4 waves handles 64 nodes: gather into LDS [64][72] fp16, then
// each wave runs the 16x64 MFMA tile from LDS. No agg16 global round-trip.

__global__ void __launch_bounds__(256) node_gemm_kernel(
        const int* __restrict__ noff, const int* __restrict__ nlist,
        const uint4* __restrict__ efeat16B, const float* __restrict__ dinv,
        const float* __restrict__ W, const float* __restrict__ bvec,
        __half* __restrict__ outr16, float* __restrict__ partials) {
    __shared__ __half aggT[64][72];   // padded: row stride 144B avoids bank conflicts
    __shared__ half8 so8[4][16][9];
    __shared__ float sred[4][128];
    int tid = threadIdx.x;

    // ---- phase A: gather (4 lanes per node, 64 nodes) ----
    {
        int nn = tid >> 2, q = tid & 3;
        int n = blockIdx.x * 64 + nn;
        float8 l0 = (float8)0.f, h0 = (float8)0.f;
        if (n < N_NODES) {
            int s = noff[n], t = noff[n + 1];
            float8 l1 = (float8)0.f, h1 = (float8)0.f;
            int j = s;
            for (; j + 1 < t; j += 2) {
                int e0 = __ldg(&nlist[j]), e1 = __ldg(&nlist[j + 1]);
                uint4 v0 = __ldg(&efeat16B[(size_t)e0 * 4 + q]);
                uint4 v1 = __ldg(&efeat16B[(size_t)e1 * 4 + q]);
                l0 += fp8x8_to_f32u(v0.x, v0.y); h0 += fp8x8_to_f32u(v0.z, v0.w);
                l1 += fp8x8_to_f32u(v1.x, v1.y); h1 += fp8x8_to_f32u(v1.z, v1.w);
            }
            if (j < t) {
                uint4 v0 = __ldg(&efeat16B[(size_t)__ldg(&nlist[j]) * 4 + q]);
                l0 += fp8x8_to_f32u(v0.x, v0.y); h0 += fp8x8_to_f32u(v0.z, v0.w);
            }
            l0 += l1; h0 += h1;
            float dv = dinv[n];
            l0 *= dv; h0 *= dv;
        }
        *(half8*)&aggT[nn][q * 16]     = cvt16(l0);
        *(half8*)&aggT[nn][q * 16 + 8] = cvt16(h0);
    }
    __syncthreads();

    // ---- phase B: per-wave 16x64 MFMA tile from LDS ----
    int w = tid >> 6, lane = tid & 63;
    int l15 = lane & 15, rg = lane >> 4;
    __half* so_h = (__half*)so8[w];

    f16x8 bf[4][2];
    #pragma unroll
    for (int c = 0; c < 4; ++c)
        #pragma unroll
        for (int kk = 0; kk < 2; ++kk)
            #pragma unroll
            for (int j = 0; j < 8; ++j) {
                int k = kk * 32 + rg * 8 + j;
                bf[c][kk][j] = (_Float16)W[k * 64 + c * 16 + l15];
            }
    float bias[4];
    #pragma unroll
    for (int c = 0; c < 4; ++c) bias[c] = bvec[c * 16 + l15];

    int n0 = blockIdx.x * 64 + w * 16;
    f16x8 a0 = *(const f16x8*)&aggT[w * 16 + l15][rg * 8];
    f16x8 a1 = *(const f16x8*)&aggT[w * 16 + l15][32 + rg * 8];
    float dv[4];
    #pragma unroll
    for (int i = 0; i < 4; ++i) {
        int nr = n0 + rg * 4 + i;
        dv[i] = (nr < N_NODES) ? dinv[nr] : 0.f;
    }
    float sa[4], sb[4];
    #pragma unroll
    for (int c = 0; c < 4; ++c) {
        f32x4 acc = {0.f, 0.f, 0.f, 0.f};
        acc = __builtin_amdgcn_mfma_f32_16x16x32_f16(a0, bf[c][0], acc, 0, 0, 0);
        acc = __builtin_amdgcn_mfma_f32_16x16x32_f16(a1, bf[c][1], acc, 0, 0, 0);
        float va = 0.f, vb = 0.f;
        #pragma unroll
        for (int i = 0; i < 4; ++i) {
            float vv = (dv[i] > 0.f) ? (acc[i] + bias[c]) : 0.f;
            va += vv; vb += vv * vv;
            so_h[(rg * 4 + i) * 72 + c * 16 + l15] = __float2half_rn(vv);
        }
        sa[c] = va; sb[c] = vb;
    }
    // coalesced row write-back (guarded for the last partial block)
    #pragma unroll
    for (int it = 0; it < 2; ++it) {
        int row = (lane >> 3) + it * 8;
        if (n0 + row < N_NODES) {
            half8 v = *(half8*)&so_h[row * 72 + (lane & 7) * 8];
            *(half8*)&outr16[(size_t)(n0 + row) * 64 + (lane & 7) * 8] = v;
        }
    }
    // ---- BN partials: wave-lane reduce -> block reduce -> one store ----
    #pragma unroll
    for (int c = 0; c < 4; ++c) {
        sa[c] += __shfl_xor(sa[c], 16); sa[c] += __shfl_xor(sa[c], 32);
        sb[c] += __shfl_xor(sb[c], 16); sb[c] += __shfl_xor(sb[c], 32);
    }
    if (rg == 0) {
        #pragma unroll
        for (int c = 0; c < 4; ++c) {
            sred[w][c * 16 + l15]      = sa[c];
            sred[w][64 + c * 16 + l15] = sb[c];
        }
    }
    __syncthreads();
    if (tid < 128) {
        float v = sred[0][tid] + sred[1][tid] + sred[2][tid] + sred[3][tid];
        partials[(size_t)blockIdx.x * 128 + tid] = v;
    }
}

// ---------------- reduce partials + BN finalize: 64 blocks, one feature each ----------------

__global__ void __launch_bounds__(256) reduce_bnfin(
        const float* __restrict__ partials, const float* __restrict__ gamma,
        const float* __restrict__ beta, float* __restrict__ scsh) {
    __shared__ float ra[256];
    __shared__ float rb[256];
    int f = blockIdx.x, tid = threadIdx.x;
    float a = 0.f, b = 0.f;
    for (int j = tid; j < NG_BLOCKS; j += 256) {
        a += partials[(size_t)j * 128 + f];
        b += partials[(size_t)j * 128 + 64 + f];
    }
    ra[tid] = a; rb[tid] = b;
    __syncthreads();
    for (int s = 128; s > 0; s >>= 1) {
        if (tid < s) { ra[tid] += ra[tid + s]; rb[tid] += rb[tid + s]; }
        __syncthreads();
    }
    if (tid == 0) {
        const float invN = 1.f / (float)N_NODES;
        float mean = ra[0] * invN;
        float var  = rb[0] * invN - mean * mean;
        var = fmaxf(var, 0.f);
        float sc = gamma[f] * rsqrtf(var + BN_EPS);
        scsh[f]      = sc;
        scsh[64 + f] = beta[f] - mean * sc;
    }
}

// ---------------- BN apply + softplus (fp16 in, fp8 out) ----------------

__global__ void apply_kernel(const half8* __restrict__ outr8, const float* __restrict__ scsh,
                             uint2* __restrict__ h8) {
    int gid = blockIdx.x * 256 + threadIdx.x;   // over N_NODES*8 octets
    if (gid >= N_NODES * 8) return;
    int qq = gid & 7;
    float8 v = cvt8(outr8[gid]);
    float4 sc0 = ((const float4*)scsh)[qq * 2];
    float4 sc1 = ((const float4*)scsh)[qq * 2 + 1];
    float4 sh0 = ((const float4*)(scsh + 64))[qq * 2];
    float4 sh1 = ((const float4*)(scsh + 64))[qq * 2 + 1];
    float8 r;
    r[0] = softplus_f(fmaf(v[0], sc0.x, sh0.x));
    r[1] = softplus_f(fmaf(v[1], sc0.y, sh0.y));
    r[2] = softplus_f(fmaf(v[2], sc0.z, sh0.z));
    r[3] = softplus_f(fmaf(v[3], sc0.w, sh0.w));
    r[4] = softplus_f(fmaf(v[4], sc1.x, sh1.x));
    r[5] = softplus_f(fmaf(v[5], sc1.y, sh1.y));
    r[6] = softplus_f(fmaf(v[6], sc1.z, sh1.z));
    r[7] = softplus_f(fmaf(v[7], sc1.w, sh1.w));
    h8[gid] = f32_to_fp8x8(r);
}

// ---------------- fused pooling + head (batch is sorted; bounds inline) ----------------

__global__ void pool_head_kernel(const uint2* __restrict__ h8, const int* __restrict__ batch,
                                 const float* __restrict__ fcW, const float* __restrict__ fcb,
                                 const float* __restrict__ fcoW, const float* __restrict__ fcob,
                                 float* __restrict__ out) {
    __shared__ float8 part[32][8];
    __shared__ float p[64];
    __shared__ float red[128];
    __shared__ int seg[2];
    int g = blockIdx.x, tid = threadIdx.x;
    if (tid < 2) {
        int target = g + tid;
        int lo = 0, hi = N_NODES;
        while (lo < hi) {
            int mid = (lo + hi) >> 1;
            if (batch[mid] < target) lo = mid + 1; else hi = mid;
        }
        seg[tid] = lo;
    }
    __syncthreads();
    int s = seg[0], t = seg[1];
    int r = tid >> 3, q = tid & 7;   // 32 row slots x 8 octets
    float8 acc = (float8)0.f;
    for (int n = s + r; n < t; n += 32)
        acc += fp8x8_to_f32(__ldg(&h8[(size_t)n * 8 + q]));
    part[r][q] = acc;
    __syncthreads();
    for (int st = 16; st >= 1; st >>= 1) {
        if (r < st) part[r][q] += part[r + st][q];
        __syncthreads();
    }
    if (tid < 8) {
        float c = fmaxf((float)(t - s), 1.f);
        float8 v = part[0][tid];
        #pragma unroll
        for (int jj = 0; jj < 8; ++jj)
            p[tid * 8 + jj] = softplus_f(v[jj] / c);
    }
    __syncthreads();
    if (tid < 128) {
        float a = fcb[tid];
        #pragma unroll
        for (int k = 0; k < 64; ++k)
            a = fmaf(p[k], fcW[k * H_DIM + tid], a);
        red[tid] = softplus_f(a) * fcoW[tid];
    }
    __syncthreads();
    for (int st = 64; st > 0; st >>= 1) {
        if (tid < st) red[tid] += red[tid + st];
        __syncthreads();
    }
    if (tid == 0) out[g] = red[0] + fcob[0];
}

// ---------------- launch ----------------

extern "C" void kernel_launch(void* const* d_in, const int* in_sizes, int n_in,
                              void* d_out, int out_size, void* d_ws, size_t ws_size,
                              hipStream_t stream) {
    const float* x      = (const float*)d_in[0];
    const float* W_emb  = (const float*)d_in[1];
    const float* b_emb  = (const float*)d_in[2];
    const float* conv_W = (const float*)d_in[3];
    const float* conv_b = (const float*)d_in[4];
    const float* bn_g   = (const float*)d_in[5];
    const float* bn_b   = (const float*)d_in[6];
    const float* fc_W   = (const float*)d_in[7];
    const float* fc_b   = (const float*)d_in[8];
    const float* fco_W  = (const float*)d_in[9];
    const float* fco_b  = (const float*)d_in[10];
    const int* node_idx = (const int*)d_in[11];
    const int* edge_idx = (const int*)d_in[12];
    const int* batch    = (const int*)d_in[13];
    float* out = (float*)d_out;

    // ---- workspace layout ----
    uint2*  h8      = (uint2*)d_ws;                             // 800K uint2 (6.4 MB fp8)
    __half* outr16  = (__half*)(h8 + (size_t)N_NODES * 8);      // 6.4M halves
    uint2*  efeat8  = (uint2*)(outr16 + (size_t)N_NODES * 64);  // 3.2M uint2 (25.6 MB fp8)
    unsigned* stagingE = (unsigned*)(efeat8 + (size_t)N_EDGES * 8); // 1.6M u32
    unsigned* stagingN = stagingE + N_INC;                      // 1.6M u32
    float* binv    = (float*)(stagingN + N_INC);                // 400K
    float* dinv    = binv   + N_EDGES;                          // 100K
    float* scsh    = dinv   + N_NODES;                          // 128
    float* partials= scsh   + 128;                              // NG_BLOCKS*128
    int*   eoff    = (int*)(partials + (size_t)NG_BLOCKS * 128); // 400K+1
    int*   noff    = eoff  + N_EDGES + 1;                       // 100K+1
    int*   histsE  = noff  + N_NODES + 1;                       // NCHP*NBUCK
    int*   histsN  = histsE + (size_t)NCHP * NBUCK;             // NCHP*NBUCK
    int*   colsumE = histsN + (size_t)NCHP * NBUCK;             // NBUCK
    int*   colsumN = colsumE + NBUCK;                           // NBUCK
    int*   bbaseE  = colsumN + NBUCK;                           // NBUCK+1
    int*   bbaseN  = bbaseE + NBUCK + 1;                        // NBUCK+1
    int*   elist   = bbaseN + NBUCK + 1;                        // 1.6M
    int*   nlist   = elist + N_INC;                             // 1.6M

    // ---- CSR build: dual deterministic counting sort (no global atomics, u32 staging) ----
    part_hist_dual<<<NCHP, 256, 0, stream>>>(edge_idx, node_idx, histsE, histsN);
    col_scan_dual<<<2 * NBUCK, 256, 0, stream>>>(histsE, histsN, colsumE, colsumN);
    bbase_scan_dual<<<2, 512, 0, stream>>>(colsumE, colsumN, bbaseE, bbaseN);
    part_scatter_dual<<<NCHP, 256, 0, stream>>>(edge_idx, node_idx, histsE, histsN,
                                                bbaseE, bbaseN, stagingE, stagingN);
    bucket_finalize_dual<<<2 * NBUCK, 256, 0, stream>>>(stagingE, stagingN, bbaseE, bbaseN,
                                                        binv, dinv, eoff, noff, elist, nlist);

    // ---- embedding (MFMA, fp8 out) ----
    embed_mfma<<<MM_BLOCKS, 256, 0, stream>>>(x, W_emb, b_emb, h8);

    // ---- 3 hypergraph conv layers ----
    for (int l = 0; l < NUM_LAYERS; ++l) {
        const float* Wl = conv_W + (size_t)l * NODE_DIM * NODE_DIM;
        const float* bl = conv_b + (size_t)l * NODE_DIM;

        edge_agg<<<(N_EDGES + 63) / 64, 256, 0, stream>>>(eoff, elist, (const uint4*)h8,
                                                          binv, (uint4*)efeat8);
        node_gemm_kernel<<<NG_BLOCKS, 256, 0, stream>>>(noff, nlist, (const uint4*)efeat8,
                                                        dinv, Wl, bl, outr16, partials);
        reduce_bnfin<<<64, 256, 0, stream>>>(partials, bn_g + (size_t)l * 64,
                                             bn_b + (size_t)l * 64, scsh);
        apply_kernel<<<(N_NODES * 8 + 255) / 256, 256, 0, stream>>>((const half8*)outr16, scsh, h8);
    }

    // ---- fused pooling + head ----
    pool_head_kernel<<<N_GRAPHS, 256, 0, stream>>>(h8, batch, fc_W, fc_b, fco_W, fco_b, out);
}

// Round 19
// 392.340 us; speedup vs baseline: 1.0463x; 1.0140x over previous
//
#include <hip/hip_runtime.h>
#include <hip/hip_fp16.h>
#include <math.h>

#define N_NODES   100000
#define N_EDGES   400000
#define N_INC     1600000
#define N_GRAPHS  512
#define ATOM_DIM  92
#define NODE_DIM  64
#define H_DIM     128
#define NUM_LAYERS 3
#define BN_EPS    1e-5f

#define NBUCK     391      // = ceil(400000/1024) = ceil(100000/256)
#define PCHUNK    2048     // items per partition block (256 thr x 8)
#define NCHP      ((N_INC + PCHUNK - 1) / PCHUNK)   // 782 chunks
#define MM_BLOCKS 1568     // blocks for embed MFMA kernel
#define NG_BLOCKS ((N_NODES + 63) / 64)   // 1563 blocks for fused node_gemm

struct alignas(8)  half4 { __half2 a, b; };
struct alignas(16) half8 { __half2 a, b, c, d; };
typedef __attribute__((ext_vector_type(8))) float float8;
typedef __attribute__((ext_vector_type(2))) float float2v;
typedef __attribute__((ext_vector_type(4))) float f32x4;
typedef _Float16 f16x8 __attribute__((ext_vector_type(8)));

__device__ __forceinline__ float softplus_f(float x) {
    return fmaxf(x, 0.f) + log1pf(expf(-fabsf(x)));
}

__device__ __forceinline__ float8 cvt8(half8 v) {
    float2 p0 = __half22float2(v.a), p1 = __half22float2(v.b);
    float2 p2 = __half22float2(v.c), p3 = __half22float2(v.d);
    float8 r;
    r[0] = p0.x; r[1] = p0.y; r[2] = p1.x; r[3] = p1.y;
    r[4] = p2.x; r[5] = p2.y; r[6] = p3.x; r[7] = p3.y;
    return r;
}
__device__ __forceinline__ half8 cvt16(float8 v) {
    half8 r;
    r.a = __floats2half2_rn(v[0], v[1]);
    r.b = __floats2half2_rn(v[2], v[3]);
    r.c = __floats2half2_rn(v[4], v[5]);
    r.d = __floats2half2_rn(v[6], v[7]);
    return r;
}

// fp8 e4m3 (OCP) pack/unpack via gfx950 HW converters
__device__ __forceinline__ float8 fp8x8_to_f32u(unsigned lo, unsigned hi) {
    float2v l0 = __builtin_amdgcn_cvt_pk_f32_fp8((int)lo, false);
    float2v h0 = __builtin_amdgcn_cvt_pk_f32_fp8((int)lo, true);
    float2v l1 = __builtin_amdgcn_cvt_pk_f32_fp8((int)hi, false);
    float2v h1 = __builtin_amdgcn_cvt_pk_f32_fp8((int)hi, true);
    float8 r;
    r[0] = l0.x; r[1] = l0.y; r[2] = h0.x; r[3] = h0.y;
    r[4] = l1.x; r[5] = l1.y; r[6] = h1.x; r[7] = h1.y;
    return r;
}
__device__ __forceinline__ float8 fp8x8_to_f32(uint2 v) {
    return fp8x8_to_f32u(v.x, v.y);
}
__device__ __forceinline__ uint2 f32_to_fp8x8(float8 v) {
    int a = 0, b = 0;
    a = __builtin_amdgcn_cvt_pk_fp8_f32(v[0], v[1], a, false);
    a = __builtin_amdgcn_cvt_pk_fp8_f32(v[2], v[3], a, true);
    b = __builtin_amdgcn_cvt_pk_fp8_f32(v[4], v[5], b, false);
    b = __builtin_amdgcn_cvt_pk_fp8_f32(v[6], v[7], b, true);
    uint2 r; r.x = (unsigned)a; r.y = (unsigned)b;
    return r;
}

// ---------------- embedding GEMM via MFMA: h = x @ W_emb + b (fp32 in, fp8 out) ----------------

__global__ void __launch_bounds__(256) embed_mfma(
        const float* __restrict__ x, const float* __restrict__ W,
        const float* __restrict__ bvec, uint2* __restrict__ h8) {
    __shared__ half8 so8[4][16][9];   // per-wave 16x72 halves transpose staging
    int tid = threadIdx.x;
    int w = tid >> 6, lane = tid & 63;
    int l15 = lane & 15, rg = lane >> 4;
    __half* so_h = (__half*)so8[w];

    f16x8 bf[4][3];
    #pragma unroll
    for (int c = 0; c < 4; ++c)
        #pragma unroll
        for (int kk = 0; kk < 3; ++kk)
            #pragma unroll
            for (int j = 0; j < 8; ++j) {
                int k = kk * 32 + rg * 8 + j;
                bf[c][kk][j] = (k < ATOM_DIM) ? (_Float16)W[k * 64 + c * 16 + l15]
                                              : (_Float16)0.f;
            }
    float bias[4];
    #pragma unroll
    for (int c = 0; c < 4; ++c) bias[c] = bvec[c * 16 + l15];

    int wave_global = blockIdx.x * 4 + w;
    for (int tile = wave_global; tile < N_NODES / 16; tile += MM_BLOCKS * 4) {
        int n0 = tile * 16;
        const float* xrow = x + (size_t)(n0 + l15) * ATOM_DIM;
        f16x8 af[3];
        #pragma unroll
        for (int kk = 0; kk < 3; ++kk) {
            int k0 = kk * 32 + rg * 8;
            if (k0 + 8 <= ATOM_DIM) {
                float4 v0 = *(const float4*)&xrow[k0];
                float4 v1 = *(const float4*)&xrow[k0 + 4];
                af[kk][0] = (_Float16)v0.x; af[kk][1] = (_Float16)v0.y;
                af[kk][2] = (_Float16)v0.z; af[kk][3] = (_Float16)v0.w;
                af[kk][4] = (_Float16)v1.x; af[kk][5] = (_Float16)v1.y;
                af[kk][6] = (_Float16)v1.z; af[kk][7] = (_Float16)v1.w;
            } else {
                float4 v0 = *(const float4*)&xrow[88];
                af[kk][0] = (_Float16)v0.x; af[kk][1] = (_Float16)v0.y;
                af[kk][2] = (_Float16)v0.z; af[kk][3] = (_Float16)v0.w;
                af[kk][4] = (_Float16)0.f;  af[kk][5] = (_Float16)0.f;
                af[kk][6] = (_Float16)0.f;  af[kk][7] = (_Float16)0.f;
            }
        }
        #pragma unroll
        for (int c = 0; c < 4; ++c) {
            f32x4 acc = {0.f, 0.f, 0.f, 0.f};
            acc = __builtin_amdgcn_mfma_f32_16x16x32_f16(af[0], bf[c][0], acc, 0, 0, 0);
            acc = __builtin_amdgcn_mfma_f32_16x16x32_f16(af[1], bf[c][1], acc, 0, 0, 0);
            acc = __builtin_amdgcn_mfma_f32_16x16x32_f16(af[2], bf[c][2], acc, 0, 0, 0);
            #pragma unroll
            for (int i = 0; i < 4; ++i)
                so_h[(rg * 4 + i) * 72 + c * 16 + l15] = __float2half_rn(acc[i] + bias[c]);
        }
        #pragma unroll
        for (int it = 0; it < 2; ++it) {
            int row = (lane >> 3) + it * 8;
            half8 v = *(half8*)&so_h[row * 72 + (lane & 7) * 8];
            h8[(size_t)(n0 + row) * 8 + (lane & 7)] = f32_to_fp8x8(cvt8(v));
        }
    }
}

// ---------------- CSR build: dual deterministic counting sort (u32 staging) ----------------
// E staging word: (local_edge_key[10b] << 17) | node_id[17b]
// N staging word: (local_node_key[8b] << 19) | edge_id[19b]

__global__ void __launch_bounds__(256) part_hist_dual(
        const int* __restrict__ ekey, const int* __restrict__ nkey,
        int* __restrict__ histsE, int* __restrict__ histsN) {
    __shared__ int hE[NBUCK];
    __shared__ int hN[NBUCK];
    int tid = threadIdx.x;
    int base = blockIdx.x * PCHUNK;
    for (int i = tid; i < NBUCK; i += 256) { hE[i] = 0; hN[i] = 0; }
    __syncthreads();
    #pragma unroll
    for (int k = 0; k < 8; ++k) {
        int i = base + tid + k * 256;
        if (i < N_INC) {
            atomicAdd(&hE[ekey[i] >> 10], 1);
            atomicAdd(&hN[nkey[i] >> 8], 1);
        }
    }
    __syncthreads();
    for (int i = tid; i < NBUCK; i += 256) {
        histsE[(size_t)blockIdx.x * NBUCK + i] = hE[i];
        histsN[(size_t)blockIdx.x * NBUCK + i] = hN[i];
    }
}

__global__ void __launch_bounds__(256) col_scan_dual(
        int* __restrict__ histsE, int* __restrict__ histsN,
        int* __restrict__ colsumE, int* __restrict__ colsumN) {
    __shared__ int ws[256];
    int which = blockIdx.x >= NBUCK;
    int i = which ? (blockIdx.x - NBUCK) : blockIdx.x;
    int* hists = which ? histsN : histsE;
    int* colsum = which ? colsumN : colsumE;
    int tid = threadIdx.x;
    int v[4];
    int loc = 0;
    #pragma unroll
    for (int k = 0; k < 4; ++k) {
        int b = tid * 4 + k;
        v[k] = (b < NCHP) ? hists[(size_t)b * NBUCK + i] : 0;
        loc += v[k];
    }
    ws[tid] = loc;
    __syncthreads();
    for (int off = 1; off < 256; off <<= 1) {
        int t = (tid >= off) ? ws[tid - off] : 0;
        __syncthreads();
        ws[tid] += t;
        __syncthreads();
    }
    int run = ws[tid] - loc;
    if (tid == 255) colsum[i] = ws[255];
    #pragma unroll
    for (int k = 0; k < 4; ++k) {
        int b = tid * 4 + k;
        if (b < NCHP) hists[(size_t)b * NBUCK + i] = run;
        run += v[k];
    }
}

__global__ void bbase_scan_dual(const int* __restrict__ colsumE, const int* __restrict__ colsumN,
                                int* __restrict__ bbaseE, int* __restrict__ bbaseN) {
    __shared__ int sh[512];
    const int* colsum = blockIdx.x ? colsumN : colsumE;
    int* bbase = blockIdx.x ? bbaseN : bbaseE;
    int tid = threadIdx.x;   // 512 threads
    int v = (tid < NBUCK) ? colsum[tid] : 0;
    sh[tid] = v;
    __syncthreads();
    for (int off = 1; off < 512; off <<= 1) {
        int t = (tid >= off) ? sh[tid - off] : 0;
        __syncthreads();
        sh[tid] += t;
        __syncthreads();
    }
    if (tid <= NBUCK)
        bbase[tid] = (tid == 0) ? 0 : sh[tid - 1];
}

__global__ void __launch_bounds__(256) part_scatter_dual(
        const int* __restrict__ ekey, const int* __restrict__ nkey,
        const int* __restrict__ histsE, const int* __restrict__ histsN,
        const int* __restrict__ bbaseE, const int* __restrict__ bbaseN,
        unsigned* __restrict__ stagingE, unsigned* __restrict__ stagingN) {
    __shared__ int curE[NBUCK];
    __shared__ int curN[NBUCK];
    int tid = threadIdx.x;
    int base = blockIdx.x * PCHUNK;
    int kE[8], kN[8];
    #pragma unroll
    for (int k = 0; k < 8; ++k) {
        int i = base + tid + k * 256;
        bool ok = (i < N_INC);
        kE[k] = ok ? ekey[i] : -1;
        kN[k] = ok ? nkey[i] : 0;
    }
    for (int i = tid; i < NBUCK; i += 256) {
        curE[i] = bbaseE[i] + histsE[(size_t)blockIdx.x * NBUCK + i];
        curN[i] = bbaseN[i] + histsN[(size_t)blockIdx.x * NBUCK + i];
    }
    __syncthreads();
    #pragma unroll
    for (int k = 0; k < 8; ++k) {
        if (kE[k] >= 0) {
            int pe = atomicAdd(&curE[kE[k] >> 10], 1);
            stagingE[pe] = ((unsigned)(kE[k] & 1023) << 17) | (unsigned)kN[k];
            int pn = atomicAdd(&curN[kN[k] >> 8], 1);
            stagingN[pn] = ((unsigned)(kN[k] & 255) << 19) | (unsigned)kE[k];
        }
    }
}

template<int RANGE, int PAYBITS>
__device__ void finalize_impl(const unsigned* __restrict__ staging,
                              const int* __restrict__ bbase, int b,
                              int nIds, float* __restrict__ inv,
                              int* __restrict__ off, int* __restrict__ list,
                              int* hist, int* wsum) {
    const int PER = RANGE / 256;
    const unsigned PAYMASK = (1u << PAYBITS) - 1u;
    int tid = threadIdx.x;
    int s = bbase[b], t = bbase[b + 1];
    int id0 = b * RANGE;
    for (int i = tid; i < RANGE; i += 256) hist[i] = 0;
    __syncthreads();
    for (int j = s + tid; j < t; j += 256) {
        unsigned key = staging[j] >> PAYBITS;
        atomicAdd(&hist[key], 1);
    }
    __syncthreads();
    int base0 = tid * PER;
    int vals[PER];
    int local = 0;
    #pragma unroll
    for (int k = 0; k < PER; ++k) { vals[k] = hist[base0 + k]; local += vals[k]; }
    wsum[tid] = local;
    __syncthreads();
    for (int o = 1; o < 256; o <<= 1) {
        int tv = (tid >= o) ? wsum[tid - o] : 0;
        __syncthreads();
        wsum[tid] += tv;
        __syncthreads();
    }
    int run = wsum[tid] - local;
    #pragma unroll
    for (int k = 0; k < PER; ++k) {
        int id = id0 + base0 + k;
        int gpos = s + run;
        if (id < nIds) {
            off[id] = gpos;
            inv[id] = vals[k] > 0 ? 1.f / (float)vals[k] : 0.f;
        } else if (id == nIds) {
            off[nIds] = gpos;
        }
        hist[base0 + k] = gpos;
        run += vals[k];
    }
    __syncthreads();
    for (int j = s + tid; j < t; j += 256) {
        unsigned it = staging[j];
        unsigned key = it >> PAYBITS;
        int pos = atomicAdd(&hist[key], 1);
        list[pos] = (int)(it & PAYMASK);
    }
}

__global__ void __launch_bounds__(256) bucket_finalize_dual(
        const unsigned* __restrict__ stagingE, const unsigned* __restrict__ stagingN,
        const int* __restrict__ bbaseE, const int* __restrict__ bbaseN,
        float* __restrict__ binv, float* __restrict__ dinv,
        int* __restrict__ eoff, int* __restrict__ noff,
        int* __restrict__ elist, int* __restrict__ nlist) {
    __shared__ int hist[1024];
    __shared__ int wsum[256];
    if (blockIdx.x < NBUCK) {
        finalize_impl<1024, 17>(stagingE, bbaseE, blockIdx.x, N_EDGES, binv, eoff, elist,
                                hist, wsum);
    } else {
        finalize_impl<256, 19>(stagingN, bbaseN, blockIdx.x - NBUCK, N_NODES, dinv, noff, nlist,
                               hist, wsum);
    }
}

// ---------------- edge aggregation (4-lane groups, 16B/lane requests) ----------------

__global__ void __launch_bounds__(256) edge_agg(
        const int* __restrict__ eoff, const int* __restrict__ elist,
        const uint4* __restrict__ h16B, const float* __restrict__ binv,
        uint4* __restrict__ efeat16B) {
    int e = blockIdx.x * 64 + (threadIdx.x >> 2);
    if (e >= N_EDGES) return;
    int q = threadIdx.x & 3;
    int s = eoff[e], t = eoff[e + 1];
    float8 alo = (float8)0.f, ahi = (float8)0.f;
    float8 blo = (float8)0.f, bhi = (float8)0.f;
    int j = s;
    for (; j + 1 < t; j += 2) {
        int n0 = __ldg(&elist[j]), n1 = __ldg(&elist[j + 1]);
        uint4 v0 = __ldg(&h16B[(size_t)n0 * 4 + q]);
        uint4 v1 = __ldg(&h16B[(size_t)n1 * 4 + q]);
        alo += fp8x8_to_f32u(v0.x, v0.y); ahi += fp8x8_to_f32u(v0.z, v0.w);
        blo += fp8x8_to_f32u(v1.x, v1.y); bhi += fp8x8_to_f32u(v1.z, v1.w);
    }
    if (j < t) {
        uint4 v0 = __ldg(&h16B[(size_t)__ldg(&elist[j]) * 4 + q]);
        alo += fp8x8_to_f32u(v0.x, v0.y); ahi += fp8x8_to_f32u(v0.z, v0.w);
    }
    alo += blo; ahi += bhi;
    float bv = binv[e];
    alo *= bv; ahi *= bv;
    uint2 lo = f32_to_fp8x8(alo), hi = f32_to_fp8x8(ahi);
    uint4 st; st.x = lo.x; st.y = lo.y; st.z = hi.x; st.w = hi.y;
    efeat16B[(size_t)e * 4 + q] = st;
}

// ---------------- fused node aggregation + MFMA GEMM + BN partials ----------------
// 4 waves / 64 nodes. LDS overlay: aggT [64][72] fp16 is consumed into registers
// (a0/a1) right after the gather barrier, then the same memory is reused as the
// per-wave transpose staging so8. 4-deep gather load chains.

__global__ void __launch_bounds__(256) node_gemm_kernel(
        const int* __restrict__ noff, const int* __restrict__ nlist,
        const uint4* __restrict__ efeat16B, const float* __restrict__ dinv,
        const float* __restrict__ W, const float* __restrict__ bvec,
        __half* __restrict__ outr16, float* __restrict__ partials) {
    __shared__ __half aggT[64][72];   // 9216 B; reused as so8[4][16][72] after consumption
    __shared__ float sred[4][128];
    int tid = threadIdx.x;

    // ---- phase A: gather (4 lanes per node, 64 nodes, 4-deep chains) ----
    {
        int nn = tid >> 2, q = tid & 3;
        int n = blockIdx.x * 64 + nn;
        float8 l0 = (float8)0.f, h0 = (float8)0.f;
        if (n < N_NODES) {
            int s = noff[n], t = noff[n + 1];
            float8 l1 = (float8)0.f, h1 = (float8)0.f;
            float8 l2 = (float8)0.f, h2 = (float8)0.f;
            float8 l3 = (float8)0.f, h3 = (float8)0.f;
            int j = s;
            for (; j + 3 < t; j += 4) {
                int e0 = __ldg(&nlist[j]),     e1 = __ldg(&nlist[j + 1]);
                int e2 = __ldg(&nlist[j + 2]), e3 = __ldg(&nlist[j + 3]);
                uint4 v0 = __ldg(&efeat16B[(size_t)e0 * 4 + q]);
                uint4 v1 = __ldg(&efeat16B[(size_t)e1 * 4 + q]);
                uint4 v2 = __ldg(&efeat16B[(size_t)e2 * 4 + q]);
                uint4 v3 = __ldg(&efeat16B[(size_t)e3 * 4 + q]);
                l0 += fp8x8_to_f32u(v0.x, v0.y); h0 += fp8x8_to_f32u(v0.z, v0.w);
                l1 += fp8x8_to_f32u(v1.x, v1.y); h1 += fp8x8_to_f32u(v1.z, v1.w);
                l2 += fp8x8_to_f32u(v2.x, v2.y); h2 += fp8x8_to_f32u(v2.z, v2.w);
                l3 += fp8x8_to_f32u(v3.x, v3.y); h3 += fp8x8_to_f32u(v3.z, v3.w);
            }
            for (; j < t; ++j) {
                uint4 v0 = __ldg(&efeat16B[(size_t)__ldg(&nlist[j]) * 4 + q]);
                l0 += fp8x8_to_f32u(v0.x, v0.y); h0 += fp8x8_to_f32u(v0.z, v0.w);
            }
            l0 += l1; l2 += l3; l0 += l2;
            h0 += h1; h2 += h3; h0 += h2;
            float dv = dinv[n];
            l0 *= dv; h0 *= dv;
        }
        *(half8*)&aggT[nn][q * 16]     = cvt16(l0);
        *(half8*)&aggT[nn][q * 16 + 8] = cvt16(h0);
    }
    __syncthreads();

    // ---- phase B: per-wave 16x64 MFMA tile; consume aggT into registers first ----
    int w = tid >> 6, lane = tid & 63;
    int l15 = lane & 15, rg = lane >> 4;
    __half* so_h = &aggT[w * 16][0];   // overlay: wave w reuses rows [16w,16w+16)

    f16x8 a0 = *(const f16x8*)&aggT[w * 16 + l15][rg * 8];
    f16x8 a1 = *(const f16x8*)&aggT[w * 16 + l15][32 + rg * 8];
    __syncthreads();   // all aggT reads complete before overlay writes

    f16x8 bf[4][2];
    #pragma unroll
    for (int c = 0; c < 4; ++c)
        #pragma unroll
        for (int kk = 0; kk < 2; ++kk)
            #pragma unroll
            for (int j = 0; j < 8; ++j) {
                int k = kk * 32 + rg * 8 + j;
                bf[c][kk][j] = (_Float16)W[k * 64 + c * 16 + l15];
            }
    float bias[4];
    #pragma unroll
    for (int c = 0; c < 4; ++c) bias[c] = bvec[c * 16 + l15];

    int n0 = blockIdx.x * 64 + w * 16;
    float dv[4];
    #pragma unroll
    for (int i = 0; i < 4; ++i) {
        int nr = n0 + rg * 4 + i;
        dv[i] = (nr < N_NODES) ? dinv[nr] : 0.f;
    }
    float sa[4], sb[4];
    #pragma unroll
    for (int c = 0; c < 4; ++c) {
        f32x4 acc = {0.f, 0.f, 0.f, 0.f};
        acc = __builtin_amdgcn_mfma_f32_16x16x32_f16(a0, bf[c][0], acc, 0, 0, 0);
        acc = __builtin_amdgcn_mfma_f32_16x16x32_f16(a1, bf[c][1], acc, 0, 0, 0);
        float va = 0.f, vb = 0.f;
        #pragma unroll
        for (int i = 0; i < 4; ++i) {
            float vv = (dv[i] > 0.f) ? (acc[i] + bias[c]) : 0.f;
            va += vv; vb += vv * vv;
            so_h[(rg * 4 + i) * 72 + c * 16 + l15] = __float2half_rn(vv);
        }
        sa[c] = va; sb[c] = vb;
    }
    // coalesced row write-back (guarded for the last partial block)
    #pragma unroll
    for (int it = 0; it < 2; ++it) {
        int row = (lane >> 3) + it * 8;
        if (n0 + row < N_NODES) {
            half8 v = *(half8*)&so_h[row * 72 + (lane & 7) * 8];
            *(half8*)&outr16[(size_t)(n0 + row) * 64 + (lane & 7) * 8] = v;
        }
    }
    // ---- BN partials: wave-lane reduce -> block reduce -> one store ----
    #pragma unroll
    for (int c = 0; c < 4; ++c) {
        sa[c] += __shfl_xor(sa[c], 16); sa[c] += __shfl_xor(sa[c], 32);
        sb[c] += __shfl_xor(sb[c], 16); sb[c] += __shfl_xor(sb[c], 32);
    }
    if (rg == 0) {
        #pragma unroll
        for (int c = 0; c < 4; ++c) {
            sred[w][c * 16 + l15]      = sa[c];
            sred[w][64 + c * 16 + l15] = sb[c];
        }
    }
    __syncthreads();
    if (tid < 128) {
        float v = sred[0][tid] + sred[1][tid] + sred[2][tid] + sred[3][tid];
        partials[(size_t)blockIdx.x * 128 + tid] = v;
    }
}

// ---------------- reduce partials + BN finalize: 64 blocks, one feature each ----------------

__global__ void __launch_bounds__(256) reduce_bnfin(
        const float* __restrict__ partials, const float* __restrict__ gamma,
        const float* __restrict__ beta, float* __restrict__ scsh) {
    __shared__ float ra[256];
    __shared__ float rb[256];
    int f = blockIdx.x, tid = threadIdx.x;
    float a = 0.f, b = 0.f;
    for (int j = tid; j < NG_BLOCKS; j += 256) {
        a += partials[(size_t)j * 128 + f];
        b += partials[(size_t)j * 128 + 64 + f];
    }
    ra[tid] = a; rb[tid] = b;
    __syncthreads();
    for (int s = 128; s > 0; s >>= 1) {
        if (tid < s) { ra[tid] += ra[tid + s]; rb[tid] += rb[tid + s]; }
        __syncthreads();
    }
    if (tid == 0) {
        const float invN = 1.f / (float)N_NODES;
        float mean = ra[0] * invN;
        float var  = rb[0] * invN - mean * mean;
        var = fmaxf(var, 0.f);
        float sc = gamma[f] * rsqrtf(var + BN_EPS);
        scsh[f]      = sc;
        scsh[64 + f] = beta[f] - mean * sc;
    }
}

// ---------------- BN apply + softplus (fp16 in, fp8 out) ----------------

__global__ void apply_kernel(const half8* __restrict__ outr8, const float* __restrict__ scsh,
                             uint2* __restrict__ h8) {
    int gid = blockIdx.x * 256 + threadIdx.x;   // over N_NODES*8 octets
    if (gid >= N_NODES * 8) return;
    int qq = gid & 7;
    float8 v = cvt8(outr8[gid]);
    float4 sc0 = ((const float4*)scsh)[qq * 2];
    float4 sc1 = ((const float4*)scsh)[qq * 2 + 1];
    float4 sh0 = ((const float4*)(scsh + 64))[qq * 2];
    float4 sh1 = ((const float4*)(scsh + 64))[qq * 2 + 1];
    float8 r;
    r[0] = softplus_f(fmaf(v[0], sc0.x, sh0.x));
    r[1] = softplus_f(fmaf(v[1], sc0.y, sh0.y));
    r[2] = softplus_f(fmaf(v[2], sc0.z, sh0.z));
    r[3] = softplus_f(fmaf(v[3], sc0.w, sh0.w));
    r[4] = softplus_f(fmaf(v[4], sc1.x, sh1.x));
    r[5] = softplus_f(fmaf(v[5], sc1.y, sh1.y));
    r[6] = softplus_f(fmaf(v[6], sc1.z, sh1.z));
    r[7] = softplus_f(fmaf(v[7], sc1.w, sh1.w));
    h8[gid] = f32_to_fp8x8(r);
}

// ---------------- fused pooling + head (batch is sorted; bounds inline) ----------------

__global__ void pool_head_kernel(const uint2* __restrict__ h8, const int* __restrict__ batch,
                                 const float* __restrict__ fcW, const float* __restrict__ fcb,
                                 const float* __restrict__ fcoW, const float* __restrict__ fcob,
                                 float* __restrict__ out) {
    __shared__ float8 part[32][8];
    __shared__ float p[64];
    __shared__ float red[128];
    __shared__ int seg[2];
    int g = blockIdx.x, tid = threadIdx.x;
    if (tid < 2) {
        int target = g + tid;
        int lo = 0, hi = N_NODES;
        while (lo < hi) {
            int mid = (lo + hi) >> 1;
            if (batch[mid] < target) lo = mid + 1; else hi = mid;
        }
        seg[tid] = lo;
    }
    __syncthreads();
    int s = seg[0], t = seg[1];
    int r = tid >> 3, q = tid & 7;   // 32 row slots x 8 octets
    float8 acc = (float8)0.f;
    for (int n = s + r; n < t; n += 32)
        acc += fp8x8_to_f32(__ldg(&h8[(size_t)n * 8 + q]));
    part[r][q] = acc;
    __syncthreads();
    for (int st = 16; st >= 1; st >>= 1) {
        if (r < st) part[r][q] += part[r + st][q];
        __syncthreads();
    }
    if (tid < 8) {
        float c = fmaxf((float)(t - s), 1.f);
        float8 v = part[0][tid];
        #pragma unroll
        for (int jj = 0; jj < 8; ++jj)
            p[tid * 8 + jj] = softplus_f(v[jj] / c);
    }
    __syncthreads();
    if (tid < 128) {
        float a = fcb[tid];
        #pragma unroll
        for (int k = 0; k < 64; ++k)
            a = fmaf(p[k], fcW[k * H_DIM + tid], a);
        red[tid] = softplus_f(a) * fcoW[tid];
    }
    __syncthreads();
    for (int st = 64; st > 0; st >>= 1) {
        if (tid < st) red[tid] += red[tid + st];
        __syncthreads();
    }
    if (tid == 0) out[g] = red[0] + fcob[0];
}

// ---------------- launch ----------------

extern "C" void kernel_launch(void* const* d_in, const int* in_sizes, int n_in,
                              void* d_out, int out_size, void* d_ws, size_t ws_size,
                              hipStream_t stream) {
    const float* x      = (const float*)d_in[0];
    const float* W_emb  = (const float*)d_in[1];
    const float* b_emb  = (const float*)d_in[2];
    const float* conv_W = (const float*)d_in[3];
    const float* conv_b = (const float*)d_in[4];
    const float* bn_g   = (const float*)d_in[5];
    const float* bn_b   = (const float*)d_in[6];
    const float* fc_W   = (const float*)d_in[7];
    const float* fc_b   = (const float*)d_in[8];
    const float* fco_W  = (const float*)d_in[9];
    const float* fco_b  = (const float*)d_in[10];
    const int* node_idx = (const int*)d_in[11];
    const int* edge_idx = (const int*)d_in[12];
    const int* batch    = (const int*)d_in[13];
    float* out = (float*)d_out;

    // ---- workspace layout ----
    uint2*  h8      = (uint2*)d_ws;                             // 800K uint2 (6.4 MB fp8)
    __half* outr16  = (__half*)(h8 + (size_t)N_NODES * 8);      // 6.4M halves
    uint2*  efeat8  = (uint2*)(outr16 + (size_t)N_NODES * 64);  // 3.2M uint2 (25.6 MB fp8)
    unsigned* stagingE = (unsigned*)(efeat8 + (size_t)N_EDGES * 8); // 1.6M u32
    unsigned* stagingN = stagingE + N_INC;                      // 1.6M u32
    float* binv    = (float*)(stagingN + N_INC);                // 400K
    float* dinv    = binv   + N_EDGES;                          // 100K
    float* scsh    = dinv   + N_NODES;                          // 128
    float* partials= scsh   + 128;                              // NG_BLOCKS*128
    int*   eoff    = (int*)(partials + (size_t)NG_BLOCKS * 128); // 400K+1
    int*   noff    = eoff  + N_EDGES + 1;                       // 100K+1
    int*   histsE  = noff  + N_NODES + 1;                       // NCHP*NBUCK
    int*   histsN  = histsE + (size_t)NCHP * NBUCK;             // NCHP*NBUCK
    int*   colsumE = histsN + (size_t)NCHP * NBUCK;             // NBUCK
    int*   colsumN = colsumE + NBUCK;                           // NBUCK
    int*   bbaseE  = colsumN + NBUCK;                           // NBUCK+1
    int*   bbaseN  = bbaseE + NBUCK + 1;                        // NBUCK+1
    int*   elist   = bbaseN + NBUCK + 1;                        // 1.6M
    int*   nlist   = elist + N_INC;                             // 1.6M

    // ---- CSR build: dual deterministic counting sort (no global atomics, u32 staging) ----
    part_hist_dual<<<NCHP, 256, 0, stream>>>(edge_idx, node_idx, histsE, histsN);
    col_scan_dual<<<2 * NBUCK, 256, 0, stream>>>(histsE, histsN, colsumE, colsumN);
    bbase_scan_dual<<<2, 512, 0, stream>>>(colsumE, colsumN, bbaseE, bbaseN);
    part_scatter_dual<<<NCHP, 256, 0, stream>>>(edge_idx, node_idx, histsE, histsN,
                                                bbaseE, bbaseN, stagingE, stagingN);
    bucket_finalize_dual<<<2 * NBUCK, 256, 0, stream>>>(stagingE, stagingN, bbaseE, bbaseN,
                                                        binv, dinv, eoff, noff, elist, nlist);

    // ---- embedding (MFMA, fp8 out) ----
    embed_mfma<<<MM_BLOCKS, 256, 0, stream>>>(x, W_emb, b_emb, h8);

    // ---- 3 hypergraph conv layers ----
    for (int l = 0; l < NUM_LAYERS; ++l) {
        const float* Wl = conv_W + (size_t)l * NODE_DIM * NODE_DIM;
        const float* bl = conv_b + (size_t)l * NODE_DIM;

        edge_agg<<<(N_EDGES + 63) / 64, 256, 0, stream>>>(eoff, elist, (const uint4*)h8,
                                                          binv, (uint4*)efeat8);
        node_gemm_kernel<<<NG_BLOCKS, 256, 0, stream>>>(noff, nlist, (const uint4*)efeat8,
                                                        dinv, Wl, bl, outr16, partials);
        reduce_bnfin<<<64, 256, 0, stream>>>(partials, bn_g + (size_t)l * 64,
                                             bn_b + (size_t)l * 64, scsh);
        apply_kernel<<<(N_NODES * 8 + 255) / 256, 256, 0, stream>>>((const half8*)outr16, scsh, h8);
    }

    // ---- fused pooling + head ----
    pool_head_kernel<<<N_GRAPHS, 256, 0, stream>>>(h8, batch, fc_W, fc_b, fco_W, fco_b, out);
}